// Round 5
// baseline (193.952 us; speedup 1.0000x reference)
//
#include <hip/hip_runtime.h>
#include <hip/hip_bf16.h>

// IsometricLoss: loss = (1/N) * sum_{i,m} r[i,m] * max(||X_i||^2 + ||mu_m||^2 - 2 X_i.mu_m, 0)
// N=131072, M=128, D=128, fp32 in, fp32 scalar out.
//
// R8: R7 (zero-LDS algebraic restructure) was latency-starved: 32 rows/wave ->
// only 4096 waves = 16/CU = 50% wave-slot cap, long serial chains, every pipe
// <15% busy. Re-tile onto mfma_f32_16x16x32_bf16: 16 rows/wave -> 8192 waves =
// 32/CU (100% cap), 4-deep MFMA chains, ~56-reg working set -> fits 64-VGPR /
// 8 waves/SIMD honestly. Augmented musT' shrinks to [144x128] (8 mus tiles +
// 1 aug tile: row 128 = mu2, row 129 = ones, 130..143 = 0; all-zero tile
// dropped), 36 KB lane-packed table, L1/L2-resident. Fragment mappings are the
// verified 32x32 family renamed: A row=lane&15, kgrp=lane>>4; B col=lane&15;
// C col=lane&15, row=(lane>>4)*4+reg (m89-verified).

typedef __attribute__((ext_vector_type(8))) short  short8;   // 8 bf16 (MFMA A/B frag)
typedef __attribute__((ext_vector_type(4))) float  float4v;  // MFMA 16x16 accumulator

#if defined(__has_builtin)
#if __has_builtin(__builtin_amdgcn_cvt_pk_bf16_f32)
#define HAVE_PK_BF16 1
#endif
#endif

__device__ __forceinline__ unsigned int pk_bf16(float x, float y) {
#ifdef HAVE_PK_BF16
    typedef __attribute__((ext_vector_type(2))) __bf16 bf16x2;
    bf16x2 p = __builtin_amdgcn_cvt_pk_bf16_f32(x, y);
    return __builtin_bit_cast(unsigned int, p);
#else
    unsigned int ux = __float_as_uint(x);
    unsigned int uy = __float_as_uint(y);
    ux += 0x7fffu + ((ux >> 16) & 1u);
    uy += 0x7fffu + ((uy >> 16) & 1u);
    return (ux >> 16) | (uy & 0xffff0000u);
#endif
}

__global__ void final_reduce_kernel(const float* ws, float* out) {
    const int lane = threadIdx.x;  // 64 threads
    float t = ws[lane];
    #pragma unroll
    for (int off = 32; off > 0; off >>= 1) t += __shfl_down(t, off);
    if (lane == 0) out[0] = t * (1.0f / 131072.0f);
}

// Prelude: lane-packed A-fragment table for musT' [144 x 128] bf16.
// Entry g = (dt*4 + ks)*64 + lane holds 8 bf16:
//   musT'[dt*16 + (lane&15)][ks*32 + (lane>>4)*8 + e],  dt=0..8, ks=0..3.
// Block 0 also zeroes the 64 reduction buckets.
__global__ __launch_bounds__(256)
void build_afrag_kernel(const float* __restrict__ mus, uint4* __restrict__ afrag,
                        float* __restrict__ ws)
{
    const int g = blockIdx.x * 256 + threadIdx.x;   // 0..2303 (9 blocks)
    if (blockIdx.x == 0 && threadIdx.x < 64) ws[threadIdx.x] = 0.0f;

    const int dt   = g >> 8;         // 0..8
    const int ks   = (g >> 6) & 3;
    const int lane = g & 63;
    const int dp   = dt * 16 + (lane & 15);          // d' in [0,144)
    const int m0   = ks * 32 + (lane >> 4) * 8;      // m base

    float v[8];
    if (dp < 128) {
        #pragma unroll
        for (int e = 0; e < 8; ++e)
            v[e] = mus[(size_t)(m0 + e) * 128 + dp];       // musT[d'][m] = mus[m][d']
    } else if (dp == 128) {                                // mu2 row (exact fp32 sums)
        #pragma unroll
        for (int e = 0; e < 8; ++e) {
            const float4* row = (const float4*)(mus + (size_t)(m0 + e) * 128);
            float a = 0.0f;
            #pragma unroll 8
            for (int d4 = 0; d4 < 32; ++d4) {
                const float4 t = row[d4];
                a += t.x*t.x + t.y*t.y + t.z*t.z + t.w*t.w;
            }
            v[e] = a;
        }
    } else if (dp == 129) {                                // ones row -> rrow
        #pragma unroll
        for (int e = 0; e < 8; ++e) v[e] = 1.0f;
    } else {                                               // zero pad rows 130..143
        #pragma unroll
        for (int e = 0; e < 8; ++e) v[e] = 0.0f;
    }

    uint4 u;
    u.x = pk_bf16(v[0], v[1]);
    u.y = pk_bf16(v[2], v[3]);
    u.z = pk_bf16(v[4], v[5]);
    u.w = pk_bf16(v[6], v[7]);
    afrag[g] = u;
}

// Main: 2048 blocks x 256 threads = 8192 waves; wave wv owns rows [wv*16, wv*16+16).
// No LDS, no barriers. C[d'][i]: A = musT' frags (precomputed), B = r row frags.
__global__ __launch_bounds__(256, 8)
void isoloss_kernel(const float* __restrict__ X,
                    const float* __restrict__ r,
                    const uint4* __restrict__ afrag,
                    float* __restrict__ ws)
{
    const int tid  = threadIdx.x;
    const int wv   = blockIdx.x * 4 + (tid >> 6);   // global wave 0..8191
    const int lane = tid & 63;
    const int li   = lane & 15;                     // row-in-chunk i (C col)
    const int kg   = lane >> 4;                     // k-group 0..3 (C row-group)

    const size_t i = (size_t)wv * 16 + li;
    const float* rrow_p = r + i * 128 + kg * 8;     // this lane's k-slices of r row i
    const float* xrow_p = X + i * 128 + kg * 4;     // this lane's d-slices of X row i

    // ---- B fragments: r[i][ks*32 + kg*8 .. +7] -> bf16 (row-contiguous loads) ----
    short8 bfrag[4];
    #pragma unroll
    for (int ks = 0; ks < 4; ++ks) {
        const float4 a = *(const float4*)(rrow_p + ks * 32);
        const float4 b = *(const float4*)(rrow_p + ks * 32 + 4);
        union { short8 s8; uint4 u4; } u;
        u.u4.x = pk_bf16(a.x, a.y);
        u.u4.y = pk_bf16(a.z, a.w);
        u.u4.z = pk_bf16(b.x, b.y);
        u.u4.w = pk_bf16(b.z, b.w);
        bfrag[ks] = u.s8;
    }

    float dotp = 0.0f, x2p = 0.0f, rmu2v = 0.0f, rrowv = 0.0f;

    // ---- 9 d'-tiles of 16: y[d'][i] = sum_m musT'[d'][m] * r[i][m] ----
    #pragma unroll
    for (int dt = 0; dt < 9; ++dt) {
        short8 af[4];
        #pragma unroll
        for (int ks = 0; ks < 4; ++ks)
            af[ks] = ((const short8*)afrag)[(dt * 4 + ks) * 64 + lane];  // coalesced, L1/L2-hot

        float4v acc = {};
        #pragma unroll
        for (int ks = 0; ks < 4; ++ks)
            acc = __builtin_amdgcn_mfma_f32_16x16x32_bf16(af[ks], bfrag[ks], acc, 0, 0, 0);

        if (dt < 8) {
            // acc[j] = y[dt*16 + kg*4 + j] for row i; X float4 at d = dt*16 + kg*4.
            const float4 xq = *(const float4*)(xrow_p + dt * 16);
            dotp += xq.x*acc[0] + xq.y*acc[1] + xq.z*acc[2] + xq.w*acc[3];
            x2p  += xq.x*xq.x + xq.y*xq.y + xq.z*xq.z + xq.w*xq.w;
        } else {
            // aug tile: d'=128 (mu2 row) -> acc[0], d'=129 (ones) -> acc[1], kg==0 only;
            // kg>=1 lanes read zero rows -> contribute nothing.
            rmu2v = (kg == 0) ? acc[0] : 0.0f;
            rrowv = (kg == 0) ? acc[1] : 0.0f;
        }
    }

    // full x2_i: butterfly over the 4 lanes (kg=0..3) holding row i's d-slices
    float x2i = x2p;
    x2i += __shfl_xor(x2i, 16);
    x2i += __shfl_xor(x2i, 32);

    // per-lane partial of loss*N: -2*dot partial everywhere; x2*rrow + r.mu2 on kg==0
    float s = fmaf(-2.0f, dotp, fmaf(x2i, rrowv, rmu2v));

    // ---- wave reduce -> bucketed atomic ----
    #pragma unroll
    for (int off = 32; off > 0; off >>= 1) s += __shfl_down(s, off);
    if (lane == 0) atomicAdd(&ws[blockIdx.x & 63], s);
}

extern "C" void kernel_launch(void* const* d_in, const int* in_sizes, int n_in,
                              void* d_out, int out_size, void* d_ws, size_t ws_size,
                              hipStream_t stream) {
    const float* X   = (const float*)d_in[0];   // [131072, 128]
    const float* r   = (const float*)d_in[1];   // [131072, 128]
    const float* mus = (const float*)d_in[2];   // [128, 128]
    float* out = (float*)d_out;                 // scalar
    float* ws  = (float*)d_ws;                  // [0..64): buckets; +256B: afrag (36 KB)
    uint4* afrag = (uint4*)((char*)d_ws + 256);

    build_afrag_kernel<<<9, 256, 0, stream>>>(mus, afrag, ws);
    isoloss_kernel<<<2048, 256, 0, stream>>>(X, r, afrag, ws);
    final_reduce_kernel<<<1, 64, 0, stream>>>(ws, out);
}